// Round 11
// baseline (637.047 us; speedup 1.0000x reference)
//
#include <hip/hip_runtime.h>
#include <stdint.h>

// SChunkTransformerEncoderLayer: B=16, L=2048, C=512, HEADS=4, DK=128,
// CHUNK=16, nW=128, SHIFT=8. fp32 I/O, bf16 internal, fp32 accum.
// R11: R10's 128x256/BK=32/2-blocks-per-CU GEMM with TRIPLE-buffered LDS
//   and reads-before-barrier (m201's drain-overlap):
//   TILE(t): rd frags(buf t%3); SB; stage(t+2 -> buf (t+2)%3); MFMA_H0;
//            vmcnt(3); SB; MFMA_H1
//   - reads issue BEFORE the barrier -> the 64-deep ds_read queue drains
//     under barrier-wait skew instead of on the post-barrier critical path
//     (R10's occupancy-doubling null showed the cost is this lockstep
//     serial chain, not TLP shortage).
//   - triple buffer (3x24KB=72KB, 2 blocks/CU) makes stage(E) never touch
//     a buffer with reads in flight: E=(t+2)%3 != t%3 (this tile's reads),
//     != (t+1)%3 (next tile's); (t-1)%3's reads drained a full tile ago.
//   - vmcnt(3) retires exactly t+1's 3 loads (outstanding 6); SB publishes.
//   - nT in {16,64}: (nT-4)/3 in {4,20} exact; remainder bufs 0,1 staged,
//     2,0 drain (vmcnt(0) at nT-2).
//   attn/LN/wconv unchanged from R9/R10.
//
// Workspace (256 MiB):
//   @0    : xn_s (32M)  -> att (32M)
//   @32M  : qkv (96M, stride 1536) -> x1@32M / W1t@64M / W2t@66M / xn2@96M
//   @128M : Wqkvt(1.5M)+Wot(0.5M)+bqkv(6K) -> h (128M)

typedef unsigned short bfu;

using bf16x8 = __attribute__((ext_vector_type(8))) __bf16;
using f32x4  = __attribute__((ext_vector_type(4))) float;

union U8 { uint4 v; unsigned short s[8]; };
union F4 { float4 v; float f[4]; };
union ABFrag { uint4 u; bf16x8 f; };

__device__ __forceinline__ float bf2f(unsigned short u) {
    union { uint32_t i; float f; } c; c.i = ((uint32_t)u) << 16; return c.f;
}
__device__ __forceinline__ unsigned short f2bf(float f) {
    union { float f; uint32_t i; } c; c.f = f;
    uint32_t x = c.i;
    return (unsigned short)((x + 0x7FFFu + ((x >> 16) & 1u)) >> 16);
}
__device__ __forceinline__ uint4 pack8(float4 a, float4 b) {
    U8 o;
    o.s[0] = f2bf(a.x); o.s[1] = f2bf(a.y); o.s[2] = f2bf(a.z); o.s[3] = f2bf(a.w);
    o.s[4] = f2bf(b.x); o.s[5] = f2bf(b.y); o.s[6] = f2bf(b.z); o.s[7] = f2bf(b.w);
    return o.v;
}

#define GLDS16(gp, lp)                                                        \
    __builtin_amdgcn_global_load_lds(                                         \
        (__attribute__((address_space(1))) void*)(gp),                        \
        (__attribute__((address_space(3))) void*)(lp), 16, 0, 0)

// ---------------- weight convert+transpose: Wt[n][k] = bf16(W[k][n]) --------

__global__ __launch_bounds__(256) void wconv_kernel(
    const float* __restrict__ W, bfu* __restrict__ Wt, int K, int N)
{
    __shared__ float t[32][33];
    const int bn = blockIdx.x << 5;
    const int bk = blockIdx.y << 5;
    const int tx = threadIdx.x & 31, ty = threadIdx.x >> 5;
#pragma unroll
    for (int i = 0; i < 32; i += 8)
        t[ty + i][tx] = W[(size_t)(bk + ty + i) * N + bn + tx];
    __syncthreads();
#pragma unroll
    for (int i = 0; i < 32; i += 8)
        Wt[(size_t)(bn + ty + i) * K + bk + tx] = f2bf(t[tx][ty + i]);
}

// QKV 3-in-1 (512x512 each), z selects the source matrix
__global__ __launch_bounds__(256) void wconv3_kernel(
    const float* __restrict__ Wq, const float* __restrict__ Wk,
    const float* __restrict__ Wv, bfu* __restrict__ Wt)
{
    __shared__ float t[32][33];
    const int z = blockIdx.z;
    const float* W = (z == 0) ? Wq : (z == 1) ? Wk : Wv;
    bfu* Wo = Wt + (size_t)z * 512 * 512;
    const int bn = blockIdx.x << 5;
    const int bk = blockIdx.y << 5;
    const int tx = threadIdx.x & 31, ty = threadIdx.x >> 5;
#pragma unroll
    for (int i = 0; i < 32; i += 8)
        t[ty + i][tx] = W[(size_t)(bk + ty + i) * 512 + bn + tx];
    __syncthreads();
#pragma unroll
    for (int i = 0; i < 32; i += 8)
        Wo[(size_t)(bn + ty + i) * 512 + bk + tx] = f2bf(t[tx][ty + i]);
}

__global__ __launch_bounds__(256) void bias_concat_kernel(
    const float* __restrict__ a, const float* __restrict__ b,
    const float* __restrict__ c, float* __restrict__ o)
{
    const int t = blockIdx.x * 256 + threadIdx.x;   // grid 6*256 = 1536
    const float* src = (t < 512) ? a : (t < 1024) ? b : c;
    o[t] = src[t & 511];
}

// ---------------- LayerNorm kernels (one wave per row, 4 rows/block) -------

__global__ __launch_bounds__(256) void ln1_shift_kernel(
    const float* __restrict__ x, const float* __restrict__ g,
    const float* __restrict__ be, bfu* __restrict__ out)
{
    const int ms = (blockIdx.x << 2) + (threadIdx.x >> 6);
    const int b = ms >> 11;
    const int ls = ms & 2047;
    const int l = (ls + 8) & 2047;
    const int c0 = (threadIdx.x & 63) << 3;
    const float* xp = x + ((((size_t)(b << 11)) + l) << 9) + c0;
    F4 f0, f1; f0.v = *(const float4*)xp; f1.v = *(const float4*)(xp + 4);
    float vv[8]; float s = 0.f, sq = 0.f;
#pragma unroll
    for (int j = 0; j < 4; ++j) { vv[j] = f0.f[j]; vv[4 + j] = f1.f[j]; }
#pragma unroll
    for (int j = 0; j < 8; ++j) { s += vv[j]; sq += vv[j] * vv[j]; }
#pragma unroll
    for (int o = 32; o > 0; o >>= 1) { s += __shfl_xor(s, o); sq += __shfl_xor(sq, o); }
    const float mean = s * (1.f / 512.f);
    float var = sq * (1.f / 512.f) - mean * mean;
    var = fmaxf(var, 0.f);
    const float rstd = rsqrtf(var + 1e-12f);
    F4 g0, g1v, b0, b1;
    g0.v = *(const float4*)(g + c0);  g1v.v = *(const float4*)(g + c0 + 4);
    b0.v = *(const float4*)(be + c0); b1.v = *(const float4*)(be + c0 + 4);
    U8 o8;
#pragma unroll
    for (int j = 0; j < 4; ++j) {
        o8.s[j]     = f2bf((vv[j]     - mean) * rstd * g0.f[j]  + b0.f[j]);
        o8.s[4 + j] = f2bf((vv[4 + j] - mean) * rstd * g1v.f[j] + b1.f[j]);
    }
    *(uint4*)(out + (((size_t)ms) << 9) + c0) = o8.v;
}

__global__ __launch_bounds__(256) void ln2_kernel(
    const bfu* __restrict__ x1, const float* __restrict__ g,
    const float* __restrict__ be, bfu* __restrict__ out)
{
    const int ms = (blockIdx.x << 2) + (threadIdx.x >> 6);
    const int c0 = (threadIdx.x & 63) << 3;
    U8 u; u.v = *(const uint4*)(x1 + (((size_t)ms) << 9) + c0);
    float vv[8]; float s = 0.f, sq = 0.f;
#pragma unroll
    for (int j = 0; j < 8; ++j) { float f = bf2f(u.s[j]); vv[j] = f; s += f; sq += f * f; }
#pragma unroll
    for (int o = 32; o > 0; o >>= 1) { s += __shfl_xor(s, o); sq += __shfl_xor(sq, o); }
    const float mean = s * (1.f / 512.f);
    float var = sq * (1.f / 512.f) - mean * mean;
    var = fmaxf(var, 0.f);
    const float rstd = rsqrtf(var + 1e-12f);
    F4 g0, g1v, b0, b1;
    g0.v = *(const float4*)(g + c0);  g1v.v = *(const float4*)(g + c0 + 4);
    b0.v = *(const float4*)(be + c0); b1.v = *(const float4*)(be + c0 + 4);
    U8 o8;
#pragma unroll
    for (int j = 0; j < 4; ++j) {
        o8.s[j]     = f2bf((vv[j]     - mean) * rstd * g0.f[j]  + b0.f[j]);
        o8.s[4 + j] = f2bf((vv[4 + j] - mean) * rstd * g1v.f[j] + b1.f[j]);
    }
    *(uint4*)(out + (((size_t)ms) << 9) + c0) = o8.v;
}

// ---------------- MFMA GEMM: 128x256, BK=32, triple-buffer, 2 blk/CU ------
// 8 waves (2Mx4N), wave tile 64x64 = acc[4][4] of 16x16x32 frags.
// LDS 72KB: buf d at d*24KB; A [128][32]bf16 (8KB), B [256][32] (16KB).
// Swizzle: row r, 16B-slot s holds global chunk s ^ ((r>>1)&3); frag read
// slot = q ^ ((l15>>1)&3) (free); stage linear dest + inv-swz source.
// TILE(t, D=t%3, E=(t+2)%3):
//   rd a[4],b[4] (8 ds_read_b128, BEFORE the barrier -> drain overlaps
//   barrier skew); SB; stage 3 -> buf E (E never has reads in flight:
//   !=D, !=(t+1)%3; (t-1)%3's reads drained a tile ago); MFMA_H0;
//   vmcnt(3) (outstanding 6 -> retires t+1's 3); SB; MFMA_H1.
// EPI 0: Ob=bf16(Y)  1: Ob=bf16(relu Y)
// EPI 2: Ob[unshifted] = bf16(xres + Y*mp)   3: Ofl = bf2f(prevb) + Y

template<int EPI>
__global__ __launch_bounds__(512, 4) void mgemm(
    const bfu* __restrict__ X, const bfu* __restrict__ Wt,
    const float* __restrict__ bias,
    bfu* Ob, float* Ofl,
    const float* __restrict__ xres, const bfu* __restrict__ prevb,
    const float* __restrict__ maskpad,
    int M, int N, int K)
{
    __shared__ __align__(16) char smem[73728];   // 3 x 24KB
    const char* smc = (const char*)smem;
    float* epi = (float*)smem;

    const int t = threadIdx.x;
    const int lane = t & 63;
    const int w = t >> 6;              // 0..7
    const int wm = w >> 2, wn = w & 3; // 2 x 4 wave grid
    const int q = lane >> 4, l15 = lane & 15;

    // XCD-aware bijective block swizzle (nwg % 8 == 0 for all our grids)
    const int gx = gridDim.x;
    const int nwg = gx * gridDim.y;
    int wid = blockIdx.y * gx + blockIdx.x;
    wid = ((wid & 7) * (nwg >> 3)) + (wid >> 3);
    const int row0 = (wid / gx) << 7;   // 128-row tiles
    const int col0 = (wid % gx) << 8;   // 256-col tiles

    // staging: thread covers row t>>2 (A) / rows t>>2 and 128+(t>>2) (B);
    // global chunk (lane&3)^((lane>>3)&3); LDS dest linear t*16B.
    const int srow = t >> 2;
    const int schunk = (((lane & 3) ^ ((lane >> 3) & 3)) << 3);
    const bfu* gAp  = X  + (size_t)(row0 + srow) * K + schunk;
    const bfu* gB0p = Wt + (size_t)(col0 + srow) * K + schunk;
    const bfu* gB1p = Wt + (size_t)(col0 + 128 + srow) * K + schunk;
    bfu* lsA  = (bfu*)smem + (t << 3);      // + buf*12288 elem (24KB)

    // frag read bases (bytes): swz slot = q ^ ((l15>>1)&3)
    const int fswz = (q ^ ((l15 >> 1) & 3)) << 4;
    const int abase = (((wm << 6) + l15) << 6) + fswz;          // + mf*1024
    const int bbase = 8192 + (((wn << 6) + l15) << 6) + fswz;   // + nf*1024

    // bias preloaded into accumulators
    f32x4 acc[4][4];
    float bv[4];
#pragma unroll
    for (int j = 0; j < 4; ++j) bv[j] = bias[col0 + (wn << 6) + (j << 4) + l15];
#pragma unroll
    for (int i = 0; i < 4; ++i)
#pragma unroll
        for (int j = 0; j < 4; ++j) {
            acc[i][j][0] = bv[j]; acc[i][j][1] = bv[j];
            acc[i][j][2] = bv[j]; acc[i][j][3] = bv[j];
        }

    ABFrag a[4], b[4];

#define SB_   __builtin_amdgcn_s_barrier()
#define VM3_  asm volatile("s_waitcnt vmcnt(3)" ::: "memory")
#define VM0_  asm volatile("s_waitcnt vmcnt(0)" ::: "memory")
#define VMNOP_ do {} while (0)

#define LDA_(D)                                                               \
    _Pragma("unroll") for (int mf = 0; mf < 4; ++mf)                          \
        a[mf].u = *(const uint4*)(smc + (D)*24576 + abase + mf*1024);
#define LDB_(D)                                                               \
    _Pragma("unroll") for (int nf = 0; nf < 4; ++nf)                          \
        b[nf].u = *(const uint4*)(smc + (D)*24576 + bbase + nf*1024);
#define MFMAH_(H)                                                             \
    __builtin_amdgcn_s_setprio(1);                                            \
    _Pragma("unroll") for (int mf = 0; mf < 4; ++mf)                          \
    _Pragma("unroll") for (int nf = 2*(H); nf < 2*(H)+2; ++nf)                \
        acc[mf][nf] = __builtin_amdgcn_mfma_f32_16x16x32_bf16(                \
            a[mf].f, b[nf].f, acc[mf][nf], 0, 0, 0);                          \
    __builtin_amdgcn_s_setprio(0);
#define STG3_(BUF) do {                                                       \
    GLDS16(gAp,  lsA + (BUF)*12288);                                          \
    GLDS16(gB0p, lsA + (BUF)*12288 + 4096);                                   \
    GLDS16(gB1p, lsA + (BUF)*12288 + 8192);                                   \
    gAp += 32; gB0p += 32; gB1p += 32; } while (0)
// tile t: read buf D=t%3, stage t+2 -> buf E=(t+2)%3
#define TILE_(D, E, DOSTG, VMW) do {                                          \
    LDA_(D); LDB_(D);                                                         \
    SB_;                                                                      \
    if (DOSTG) STG3_(E);                                                      \
    MFMAH_(0);                                                                \
    VMW;                                                                      \
    SB_;                                                                      \
    MFMAH_(1);                                                                \
} while (0)

    const int nT = K >> 5;   // K in {512, 2048} -> nT in {16, 64}

    // prologue: stage t0->buf0, t1->buf1; vmcnt(3) retires t0's 3;
    // SB publishes buf0 cross-wave before tile 0's reads.
    STG3_(0);
    STG3_(1);
    VM3_;
    SB_;

    const int nG = (nT - 4) / 3;   // 4 (nT=16) or 20 (nT=64), exact
#pragma unroll 1
    for (int g = 0; g < nG; ++g) {
        TILE_(0, 2, true, VM3_);
        TILE_(1, 0, true, VM3_);
        TILE_(2, 1, true, VM3_);
    }
    TILE_(0, 2, true, VM3_);     // t = nT-4: stage -> nT-2 (buf 2)
    TILE_(1, 0, true, VM3_);     // t = nT-3: stage -> nT-1 (buf 0)
    TILE_(2, 1, false, VM0_);    // t = nT-2: drain (retires nT-1's 3)
    TILE_(0, 2, false, VMNOP_);  // t = nT-1

#undef LDA_
#undef LDB_
#undef MFMAH_
#undef STG3_
#undef TILE_

    SB_;   // all waves consumed their frags (lgkm drained) before alias

    // epilogue: per wave stage 16x64 fp32 in LDS, store coalesced
    float* epw = epi + w * 1088;                    // [16][68] = 4352B
    const int c8 = (lane & 7) << 3;
    const int r8 = lane >> 3;
    const int colg = col0 + (wn << 6) + c8;
#pragma unroll
    for (int i = 0; i < 4; ++i) {
#pragma unroll
        for (int j = 0; j < 4; ++j)
#pragma unroll
            for (int r = 0; r < 4; ++r) {
                float y = acc[i][j][r];
                if (EPI == 1) y = fmaxf(y, 0.f);
                epw[((q << 2) + r) * 68 + (j << 4) + l15] = y;
            }
        __builtin_amdgcn_wave_barrier();
#pragma unroll
        for (int h = 0; h < 2; ++h) {
            const int rr = r8 + (h << 3);
            F4 f0, f1;
            f0.v = *(const float4*)&epw[rr * 68 + c8];
            f1.v = *(const float4*)&epw[rr * 68 + c8 + 4];
            const int row_out = row0 + (wm << 6) + (i << 4) + rr;
            if (EPI == 0 || EPI == 1) {
                *(uint4*)(Ob + (size_t)row_out * N + colg) = pack8(f0.v, f1.v);
            } else if (EPI == 2) {
                const int bb2 = row_out >> 11;
                const int ls = row_out & 2047;
                const int l = (ls + 8) & 2047;      // reverse shift
                const float mp = maskpad[(bb2 << 11) + l];
                const size_t dst = ((size_t)(bb2 << 11) + l) * (size_t)N + colg;
                F4 x0, x1v;
                x0.v = *(const float4*)(xres + dst);
                x1v.v = *(const float4*)(xres + dst + 4);
                F4 o0, o1;
#pragma unroll
                for (int jj = 0; jj < 4; ++jj) {
                    o0.f[jj] = x0.f[jj]  + f0.f[jj] * mp;
                    o1.f[jj] = x1v.f[jj] + f1.f[jj] * mp;
                }
                *(uint4*)(Ob + dst) = pack8(o0.v, o1.v);
            } else { // EPI 3
                const size_t dst = (size_t)row_out * N + colg;
                U8 pb; pb.v = *(const uint4*)(prevb + dst);
                F4 o0, o1;
#pragma unroll
                for (int jj = 0; jj < 4; ++jj) {
                    o0.f[jj] = bf2f(pb.s[jj])     + f0.f[jj];
                    o1.f[jj] = bf2f(pb.s[4 + jj]) + f1.f[jj];
                }
                *(float4*)(Ofl + dst) = o0.v;
                *(float4*)(Ofl + dst + 4) = o1.v;
            }
        }
        __builtin_amdgcn_wave_barrier();
    }
}

// ---------------- Windowed attention (qkv packed, stride 1536) --------------
// float4-vectorized LDS; row stride 132 floats (528B = 33*16: aligned, and
// 528 % 128 = 16 -> 8 consecutive rows span 8 distinct 16B bank slots).

__global__ __launch_bounds__(256) void attn_kernel(
    const bfu* __restrict__ qkv, const float* __restrict__ mpad,
    bfu* __restrict__ out)
{
    __shared__ float qs[16][132];
    __shared__ float ks[16][132];
    __shared__ float vs[16][132];
    __shared__ float ps[16][17];
    const int t = threadIdx.x;
    const int wg = blockIdx.x;
    const int h = blockIdx.y;
    const int b = wg >> 7;
    const int w = wg & 127;
    const int li = t >> 4;
    const int d0 = (t & 15) << 3;
    const size_t bi = (((size_t)wg << 4) + li) * 1536 + (h << 7) + d0;
    U8 uq, uk, uv;
    uq.v = *(const uint4*)(qkv + bi);
    uk.v = *(const uint4*)(qkv + bi + 512);
    uv.v = *(const uint4*)(qkv + bi + 1024);
    F4 a0, a1;
#pragma unroll
    for (int j = 0; j < 4; ++j) { a0.f[j] = bf2f(uq.s[j]); a1.f[j] = bf2f(uq.s[4 + j]); }
    *(float4*)&qs[li][d0] = a0.v;  *(float4*)&qs[li][d0 + 4] = a1.v;
#pragma unroll
    for (int j = 0; j < 4; ++j) { a0.f[j] = bf2f(uk.s[j]); a1.f[j] = bf2f(uk.s[4 + j]); }
    *(float4*)&ks[li][d0] = a0.v;  *(float4*)&ks[li][d0 + 4] = a1.v;
#pragma unroll
    for (int j = 0; j < 4; ++j) { a0.f[j] = bf2f(uv.s[j]); a1.f[j] = bf2f(uv.s[4 + j]); }
    *(float4*)&vs[li][d0] = a0.v;  *(float4*)&vs[li][d0 + 4] = a1.v;
    __syncthreads();
    const int qi = li, ki = t & 15;
    float s = 0.f;
#pragma unroll
    for (int d = 0; d < 128; d += 4) {
        F4 qv, kv;
        qv.v = *(const float4*)&qs[qi][d];
        kv.v = *(const float4*)&ks[ki][d];
        s += qv.f[0] * kv.f[0] + qv.f[1] * kv.f[1]
           + qv.f[2] * kv.f[2] + qv.f[3] * kv.f[3];
    }
    s *= 0.088388347648318447f;
    const bool lastw = (w == 127);
    if (lastw ? (qi >= 8 && ki >= 8) : (qi < 7 && ki >= 8)) s -= 100.f;
    const int lkey = ((w << 4) + ki + 8) & 2047;
    const bool valid = mpad[(b << 11) + lkey] > 0.f;
    if (!valid) s = -1e30f;
    float mx = s;
#pragma unroll
    for (int o = 8; o > 0; o >>= 1) mx = fmaxf(mx, __shfl_xor(mx, o, 16));
    float e = __expf(s - mx);
    float sum = e;
#pragma unroll
    for (int o = 8; o > 0; o >>= 1) sum += __shfl_xor(sum, o, 16);
    float p = e / sum;
    if (!valid) p = 0.f;
    ps[qi][ki] = p;
    __syncthreads();
    F4 o0, o1;
#pragma unroll
    for (int j = 0; j < 4; ++j) { o0.f[j] = 0.f; o1.f[j] = 0.f; }
#pragma unroll
    for (int kk = 0; kk < 16; ++kk) {
        const float pw = ps[li][kk];
        F4 v0, v1;
        v0.v = *(const float4*)&vs[kk][d0];
        v1.v = *(const float4*)&vs[kk][d0 + 4];
#pragma unroll
        for (int j = 0; j < 4; ++j) {
            o0.f[j] += pw * v0.f[j];
            o1.f[j] += pw * v1.f[j];
        }
    }
    U8 o8;
#pragma unroll
    for (int j = 0; j < 4; ++j) { o8.s[j] = f2bf(o0.f[j]); o8.s[4 + j] = f2bf(o1.f[j]); }
    *(uint4*)(out + (((size_t)wg << 4) + li) * 512 + (h << 7) + d0) = o8.v;
}

// ---------------- Launch ----------------

extern "C" void kernel_launch(void* const* d_in, const int* in_sizes, int n_in,
                              void* d_out, int out_size, void* d_ws, size_t ws_size,
                              hipStream_t stream)
{
    const float* x    = (const float*)d_in[0];
    const float* mpad = (const float*)d_in[3];
    const float* Wq = (const float*)d_in[4];  const float* bq = (const float*)d_in[5];
    const float* Wk = (const float*)d_in[6];  const float* bk = (const float*)d_in[7];
    const float* Wv = (const float*)d_in[8];  const float* bv = (const float*)d_in[9];
    const float* Wo = (const float*)d_in[10]; const float* bo = (const float*)d_in[11];
    const float* g1 = (const float*)d_in[12]; const float* be1 = (const float*)d_in[13];
    const float* g2 = (const float*)d_in[14]; const float* be2 = (const float*)d_in[15];
    const float* W1 = (const float*)d_in[16]; const float* bf1 = (const float*)d_in[17];
    const float* W2 = (const float*)d_in[18]; const float* bf2 = (const float*)d_in[19];
    float* out = (float*)d_out;

    char* p = (char*)d_ws;
    const size_t MB = (size_t)1 << 20;
    bfu* xn_s = (bfu*)p;                     // @0; later att
    bfu* att  = xn_s;
    bfu* qkv  = (bfu*)(p + 32 * MB);         // 96 MiB, stride 1536
    bfu* x1   = qkv;                         // @32M after attn
    bfu* W1t  = (bfu*)(p + 64 * MB);         // 2 MiB
    bfu* W2t  = (bfu*)(p + 66 * MB);         // 2 MiB
    bfu* xn2  = (bfu*)(p + 96 * MB);         // 32 MiB
    bfu* hreg = (bfu*)(p + 128 * MB);        // 128 MiB; head holds Wqkvt/Wot early
    bfu* Wqkvt = hreg;                       // 1.5 MiB
    bfu* Wot   = hreg + 1536 * 512;          // 0.5 MiB
    float* bqkv = (float*)(hreg + 2048 * 512);  // 6 KiB

    const int M = 32768;
    dim3 blk(256);
    dim3 blk5(512);

    // pack weights/bias
    wconv3_kernel<<<dim3(16, 16, 3), blk, 0, stream>>>(Wq, Wk, Wv, Wqkvt);
    wconv_kernel<<<dim3(16, 16), blk, 0, stream>>>(Wo, Wot, 512, 512);
    bias_concat_kernel<<<dim3(6), blk, 0, stream>>>(bq, bk, bv, bqkv);

    ln1_shift_kernel<<<8192, blk, 0, stream>>>(x, g1, be1, xn_s);

    // fused QKV: [32768 x 1536], K=512
    mgemm<0><<<dim3(6, 256), blk5, 0, stream>>>(xn_s, Wqkvt, bqkv, qkv, nullptr, nullptr, nullptr, nullptr, M, 1536, 512);

    attn_kernel<<<dim3(2048, 4), blk, 0, stream>>>(qkv, mpad, att);

    // FFN weights into dead qkv region
    wconv_kernel<<<dim3(64, 16), blk, 0, stream>>>(W1, W1t, 512, 2048);
    wconv_kernel<<<dim3(16, 64), blk, 0, stream>>>(W2, W2t, 2048, 512);

    mgemm<2><<<dim3(2, 256), blk5, 0, stream>>>(att, Wot, bo, x1, nullptr, x, nullptr, mpad, M, 512, 512);

    ln2_kernel<<<8192, blk, 0, stream>>>(x1, g2, be2, xn2);

    mgemm<1><<<dim3(8, 256), blk5, 0, stream>>>(xn2, W1t, bf1, hreg, nullptr, nullptr, nullptr, nullptr, M, 2048, 512);
    mgemm<3><<<dim3(2, 256), blk5, 0, stream>>>(hreg, W2t, bf2, nullptr, out, nullptr, x1, nullptr, M, 512, 2048);
}

// Round 12
// 479.334 us; speedup vs baseline: 1.3290x; 1.3290x over previous
//
#include <hip/hip_runtime.h>
#include <stdint.h>

// SChunkTransformerEncoderLayer: B=16, L=2048, C=512, HEADS=4, DK=128,
// CHUNK=16, nW=128, SHIFT=8. fp32 I/O, bf16 internal, fp32 accum.
// R12: full revert to R9 (best verified: 487us) after R10 (occupancy null)
//   and R11 (triple-buffer -> compiler register-renaming spill, WRITE
//   +200MB) refuted further GEMM restructuring. GEMM = R7/R9 256x256
//   4-phase single-barrier structure (no spill, ~99us big-GEMM).
//   Only change vs R9: weight-pack launches consolidated:
//   - wconv4: Wq/Wk/Wv/Wo (4x 512x512 transposes) in one flat-grid launch
//   - wconvffn: W1 (512x2048) + W2 (2048x512) in one flat-grid launch
//
// Workspace (256 MiB):
//   @0    : xn_s (32M)  -> att (32M)
//   @32M  : qkv (96M, stride 1536) -> x1@32M / W1t@64M / W2t@66M / xn2@96M
//   @128M : Wqkvt(1.5M)+Wot(0.5M)+bqkv(6K) -> h (128M)

typedef unsigned short bfu;

using bf16x8 = __attribute__((ext_vector_type(8))) __bf16;
using f32x4  = __attribute__((ext_vector_type(4))) float;

union U8 { uint4 v; unsigned short s[8]; };
union F4 { float4 v; float f[4]; };
union ABFrag { uint4 u; bf16x8 f; };

__device__ __forceinline__ float bf2f(unsigned short u) {
    union { uint32_t i; float f; } c; c.i = ((uint32_t)u) << 16; return c.f;
}
__device__ __forceinline__ unsigned short f2bf(float f) {
    union { float f; uint32_t i; } c; c.f = f;
    uint32_t x = c.i;
    return (unsigned short)((x + 0x7FFFu + ((x >> 16) & 1u)) >> 16);
}
__device__ __forceinline__ uint4 pack8(float4 a, float4 b) {
    U8 o;
    o.s[0] = f2bf(a.x); o.s[1] = f2bf(a.y); o.s[2] = f2bf(a.z); o.s[3] = f2bf(a.w);
    o.s[4] = f2bf(b.x); o.s[5] = f2bf(b.y); o.s[6] = f2bf(b.z); o.s[7] = f2bf(b.w);
    return o.v;
}

#define GLDS16(gp, lp)                                                        \
    __builtin_amdgcn_global_load_lds(                                         \
        (__attribute__((address_space(1))) void*)(gp),                        \
        (__attribute__((address_space(3))) void*)(lp), 16, 0, 0)

// ---- weight packing: 4x 512x512 transposes (Wq,Wk,Wv -> Wqkvt; Wo -> Wot)
// flat grid 1024: z = b>>8 selects matrix, r = b&255 -> 16x16 32-tile grid.

__global__ __launch_bounds__(256) void wconv4_kernel(
    const float* __restrict__ Wq, const float* __restrict__ Wk,
    const float* __restrict__ Wv, const float* __restrict__ Wo,
    bfu* __restrict__ Wqkvt, bfu* __restrict__ Wot)
{
    __shared__ float t[32][33];
    const int b = blockIdx.x;
    const int z = b >> 8;
    const int r = b & 255;
    const float* W = (z == 0) ? Wq : (z == 1) ? Wk : (z == 2) ? Wv : Wo;
    bfu* Wt = (z < 3) ? (Wqkvt + (size_t)z * 512 * 512) : Wot;
    const int bn = (r & 15) << 5;
    const int bk = (r >> 4) << 5;
    const int tx = threadIdx.x & 31, ty = threadIdx.x >> 5;
#pragma unroll
    for (int i = 0; i < 32; i += 8)
        t[ty + i][tx] = W[(size_t)(bk + ty + i) * 512 + bn + tx];
    __syncthreads();
#pragma unroll
    for (int i = 0; i < 32; i += 8)
        Wt[(size_t)(bn + ty + i) * 512 + bk + tx] = f2bf(t[tx][ty + i]);
}

// ---- FFN weight packing: W1 (512x2048 -> W1t[2048][512]) and
// W2 (2048x512 -> W2t[512][2048]) in one flat launch (1024 + 1024 blocks).

__global__ __launch_bounds__(256) void wconvffn_kernel(
    const float* __restrict__ W1, const float* __restrict__ W2,
    bfu* __restrict__ W1t, bfu* __restrict__ W2t)
{
    __shared__ float t[32][33];
    const int b = blockIdx.x;
    const int tx = threadIdx.x & 31, ty = threadIdx.x >> 5;
    if (b < 1024) {            // W1: K=512, N=2048 -> 64 x 16 tiles
        const int bn = (b & 63) << 5;
        const int bk = (b >> 6) << 5;
#pragma unroll
        for (int i = 0; i < 32; i += 8)
            t[ty + i][tx] = W1[(size_t)(bk + ty + i) * 2048 + bn + tx];
        __syncthreads();
#pragma unroll
        for (int i = 0; i < 32; i += 8)
            W1t[(size_t)(bn + ty + i) * 512 + bk + tx] = f2bf(t[tx][ty + i]);
    } else {                   // W2: K=2048, N=512 -> 16 x 64 tiles
        const int r = b - 1024;
        const int bn = (r & 15) << 5;
        const int bk = (r >> 4) << 5;
#pragma unroll
        for (int i = 0; i < 32; i += 8)
            t[ty + i][tx] = W2[(size_t)(bk + ty + i) * 512 + bn + tx];
        __syncthreads();
#pragma unroll
        for (int i = 0; i < 32; i += 8)
            W2t[(size_t)(bn + ty + i) * 2048 + bk + tx] = f2bf(t[tx][ty + i]);
    }
}

__global__ __launch_bounds__(256) void bias_concat_kernel(
    const float* __restrict__ a, const float* __restrict__ b,
    const float* __restrict__ c, float* __restrict__ o)
{
    const int t = blockIdx.x * 256 + threadIdx.x;   // grid 6*256 = 1536
    const float* src = (t < 512) ? a : (t < 1024) ? b : c;
    o[t] = src[t & 511];
}

// ---------------- LayerNorm kernels (one wave per row, 4 rows/block) -------

__global__ __launch_bounds__(256) void ln1_shift_kernel(
    const float* __restrict__ x, const float* __restrict__ g,
    const float* __restrict__ be, bfu* __restrict__ out)
{
    const int ms = (blockIdx.x << 2) + (threadIdx.x >> 6);
    const int b = ms >> 11;
    const int ls = ms & 2047;
    const int l = (ls + 8) & 2047;
    const int c0 = (threadIdx.x & 63) << 3;
    const float* xp = x + ((((size_t)(b << 11)) + l) << 9) + c0;
    F4 f0, f1; f0.v = *(const float4*)xp; f1.v = *(const float4*)(xp + 4);
    float vv[8]; float s = 0.f, sq = 0.f;
#pragma unroll
    for (int j = 0; j < 4; ++j) { vv[j] = f0.f[j]; vv[4 + j] = f1.f[j]; }
#pragma unroll
    for (int j = 0; j < 8; ++j) { s += vv[j]; sq += vv[j] * vv[j]; }
#pragma unroll
    for (int o = 32; o > 0; o >>= 1) { s += __shfl_xor(s, o); sq += __shfl_xor(sq, o); }
    const float mean = s * (1.f / 512.f);
    float var = sq * (1.f / 512.f) - mean * mean;
    var = fmaxf(var, 0.f);
    const float rstd = rsqrtf(var + 1e-12f);
    F4 g0, g1v, b0, b1;
    g0.v = *(const float4*)(g + c0);  g1v.v = *(const float4*)(g + c0 + 4);
    b0.v = *(const float4*)(be + c0); b1.v = *(const float4*)(be + c0 + 4);
    U8 o8;
#pragma unroll
    for (int j = 0; j < 4; ++j) {
        o8.s[j]     = f2bf((vv[j]     - mean) * rstd * g0.f[j]  + b0.f[j]);
        o8.s[4 + j] = f2bf((vv[4 + j] - mean) * rstd * g1v.f[j] + b1.f[j]);
    }
    *(uint4*)(out + (((size_t)ms) << 9) + c0) = o8.v;
}

__global__ __launch_bounds__(256) void ln2_kernel(
    const bfu* __restrict__ x1, const float* __restrict__ g,
    const float* __restrict__ be, bfu* __restrict__ out)
{
    const int ms = (blockIdx.x << 2) + (threadIdx.x >> 6);
    const int c0 = (threadIdx.x & 63) << 3;
    U8 u; u.v = *(const uint4*)(x1 + (((size_t)ms) << 9) + c0);
    float vv[8]; float s = 0.f, sq = 0.f;
#pragma unroll
    for (int j = 0; j < 8; ++j) { float f = bf2f(u.s[j]); vv[j] = f; s += f; sq += f * f; }
#pragma unroll
    for (int o = 32; o > 0; o >>= 1) { s += __shfl_xor(s, o); sq += __shfl_xor(sq, o); }
    const float mean = s * (1.f / 512.f);
    float var = sq * (1.f / 512.f) - mean * mean;
    var = fmaxf(var, 0.f);
    const float rstd = rsqrtf(var + 1e-12f);
    F4 g0, g1v, b0, b1;
    g0.v = *(const float4*)(g + c0);  g1v.v = *(const float4*)(g + c0 + 4);
    b0.v = *(const float4*)(be + c0); b1.v = *(const float4*)(be + c0 + 4);
    U8 o8;
#pragma unroll
    for (int j = 0; j < 4; ++j) {
        o8.s[j]     = f2bf((vv[j]     - mean) * rstd * g0.f[j]  + b0.f[j]);
        o8.s[4 + j] = f2bf((vv[4 + j] - mean) * rstd * g1v.f[j] + b1.f[j]);
    }
    *(uint4*)(out + (((size_t)ms) << 9) + c0) = o8.v;
}

// ---------------- MFMA GEMM: 256x256 tile, 4 single-barrier phases --------
// (R7/R9 structure, verified ~99us big-GEMM, no spill.)
// 8 waves (2Mx4N), wave tile 128x64 = acc[8][4] of 16x16x32 frags, BK=64.
// LDS 128 KiB: buf d at d*64KB; A [256][64]bf16 at +0, B at +32KB.
// Swizzle: LDS row r, 16B-slot s holds global k-chunk (s ^ (r&7)); stage
// linear dest + inverse-swizzled global src; ds_read col ^ ((l15&7)<<4).
// Per K-tile t (buf D=t&1; stage targets t+2 -> same buf D):
//  P0: [bar] rd A(MH0)+B(NH0)          ; MFMA Q(0,0)
//  P1: [bar] rd B(NH1)                 ; MFMA Q(0,1)
//  P2: [bar] rd A(MH1); STAGE B4       ; MFMA Q(1,0)
//  P3: [bar] STAGE A4                  ; MFMA Q(1,1); vmcnt(8)
// EPI 0: Ob=bf16(Y)  1: Ob=bf16(relu Y)
// EPI 2: Ob[unshifted] = bf16(xres + Y*mp)   3: Ofl = bf2f(prevb) + Y

template<int EPI>
__global__ __launch_bounds__(512, 2) void mgemm(
    const bfu* __restrict__ X, const bfu* __restrict__ Wt,
    const float* __restrict__ bias,
    bfu* Ob, float* Ofl,
    const float* __restrict__ xres, const bfu* __restrict__ prevb,
    const float* __restrict__ maskpad,
    int M, int N, int K)
{
    __shared__ __align__(16) char smem[131072];
    bfu* smb = (bfu*)smem;
    const char* smc = (const char*)smem;
    float* epi = (float*)smem;

    const int t = threadIdx.x;
    const int lane = t & 63;
    const int w = t >> 6;              // 0..7
    const int wm = w >> 2, wn = w & 3; // 2 x 4 wave grid
    const int q = lane >> 4, l15 = lane & 15;

    // XCD-aware bijective block swizzle (nwg % 8 == 0 for all our grids)
    const int gx = gridDim.x;
    const int nwg = gx * gridDim.y;
    int wid = blockIdx.y * gx + blockIdx.x;
    wid = ((wid & 7) * (nwg >> 3)) + (wid >> 3);
    const int row0 = (wid / gx) << 8;
    const int col0 = (wid % gx) << 8;

    // staging: thread covers row (stmt*64 + w*8 + lane/8),
    // global chunk (lane&7)^((lane>>3)&7); LDS dest linear lane*16B.
    const int srow = (w << 3) + (lane >> 3);
    const int scol = (((lane & 7) ^ ((lane >> 3) & 7)) << 3);
    const bfu* gA = X  + (size_t)(row0 + srow) * K + scol;
    const bfu* gB = Wt + (size_t)(col0 + srow) * K + scol;
    bfu* lsA0 = smb + (w << 9) + (lane << 3);
    bfu* lsB0 = lsA0 + 16384;
    bfu* lsA1 = lsA0 + 32768;
    bfu* lsB1 = lsA0 + 49152;

    // frag read bases (bytes)
    const int arow = ((wm << 7) + l15) << 7;   // (wm*128+l15)*128
    const int brow = ((wn << 6) + l15) << 7;   // (wn*64 +l15)*128
    const int qb   = q << 4;
    const int swz  = (l15 & 7) << 4;

    // bias preloaded into accumulators
    f32x4 acc[8][4];
    float bv[4];
#pragma unroll
    for (int j = 0; j < 4; ++j) bv[j] = bias[col0 + (wn << 6) + (j << 4) + l15];
#pragma unroll
    for (int i = 0; i < 8; ++i)
#pragma unroll
        for (int j = 0; j < 4; ++j) {
            acc[i][j][0] = bv[j]; acc[i][j][1] = bv[j];
            acc[i][j][2] = bv[j]; acc[i][j][3] = bv[j];
        }

    ABFrag a[4][2];        // current A half (single-buffered - fits budget)
    ABFrag bb[2][2][2];    // full B tile: [NH][nf][kk], register-resident

#define SB_   __builtin_amdgcn_s_barrier()
#define VM8_  asm volatile("s_waitcnt vmcnt(8)" ::: "memory")
#define VM0_  asm volatile("s_waitcnt vmcnt(0)" ::: "memory")
#define VMNOP_ do {} while (0)

#define LDA_(D, MH)                                                           \
    _Pragma("unroll") for (int mf = 0; mf < 4; ++mf)                          \
    _Pragma("unroll") for (int kk = 0; kk < 2; ++kk)                          \
        a[mf][kk].u = *(const uint4*)(smc + (D)*65536 + arow + (MH)*8192 +    \
                                      mf*2048 + (((kk << 6) + qb) ^ swz));
#define LDB_(D, NH)                                                           \
    _Pragma("unroll") for (int nf = 0; nf < 2; ++nf)                          \
    _Pragma("unroll") for (int kk = 0; kk < 2; ++kk)                          \
        bb[NH][nf][kk].u = *(const uint4*)(smc + (D)*65536 + 32768 + brow +   \
                                      (NH)*4096 + nf*2048 +                   \
                                      (((kk << 6) + qb) ^ swz));
#define MFMAQ_(MH, NH)                                                        \
    __builtin_amdgcn_s_setprio(1);                                            \
    _Pragma("unroll") for (int mf = 0; mf < 4; ++mf)                          \
    _Pragma("unroll") for (int nf = 0; nf < 2; ++nf) {                        \
        acc[(MH)*4+mf][(NH)*2+nf] = __builtin_amdgcn_mfma_f32_16x16x32_bf16(  \
            a[mf][0].f, bb[NH][nf][0].f, acc[(MH)*4+mf][(NH)*2+nf], 0, 0, 0); \
        acc[(MH)*4+mf][(NH)*2+nf] = __builtin_amdgcn_mfma_f32_16x16x32_bf16(  \
            a[mf][1].f, bb[NH][nf][1].f, acc[(MH)*4+mf][(NH)*2+nf], 0, 0, 0);}\
    __builtin_amdgcn_s_setprio(0);
#define STGA4_(D, GA2) do {                                                   \
    GLDS16((GA2), lsA##D);                                                    \
    GLDS16((GA2) + (size_t)64  * K, lsA##D + 4096);                           \
    GLDS16((GA2) + (size_t)128 * K, lsA##D + 8192);                           \
    GLDS16((GA2) + (size_t)192 * K, lsA##D + 12288); } while (0)
#define STGB4_(D, GB2) do {                                                   \
    GLDS16((GB2), lsB##D);                                                    \
    GLDS16((GB2) + (size_t)64  * K, lsB##D + 4096);                           \
    GLDS16((GB2) + (size_t)128 * K, lsB##D + 8192);                           \
    GLDS16((GB2) + (size_t)192 * K, lsB##D + 12288); } while (0)
// single-barrier phases; tile t in buf D; stages t+2 -> same buf D
#define TILE_(D, DOSTG, VMW) do {                                             \
    SB_;                                                                      \
    LDA_(D, 0); LDB_(D, 0);                                                   \
    MFMAQ_(0, 0);                                                             \
    SB_;                                                                      \
    LDB_(D, 1);                                                               \
    MFMAQ_(0, 1);                                                             \
    SB_;                                                                      \
    LDA_(D, 1);                                                               \
    if (DOSTG) STGB4_(D, gB2);                                                \
    MFMAQ_(1, 0);                                                             \
    SB_;                                                                      \
    if (DOSTG) STGA4_(D, gA2);                                                \
    MFMAQ_(1, 1);                                                             \
    VMW;                                                                      \
} while (0)

    const int nT = K >> 6;   // K in {512, 2048} -> nT in {8, 32}, even

    // prologue: stage tiles 0 (buf0) and 1 (buf1); per-wave wait for tile0
    // (cross-wave visibility comes from the loop's first P0 barrier)
    STGA4_(0, gA); STGB4_(0, gB);
    {
        const bfu* ga1 = gA + 64; const bfu* gb1 = gB + 64;
        STGA4_(1, ga1); STGB4_(1, gb1);
    }
    VM8_;

    const bfu* gA2 = gA + 128;   // tile 2
    const bfu* gB2 = gB + 128;
#pragma unroll 1
    for (int tt = 0; tt < nT - 2; tt += 2) {
        TILE_(0, true, VM8_);
        gA2 += 64; gB2 += 64;
        TILE_(1, true, VM8_);
        gA2 += 64; gB2 += 64;
    }
    TILE_(0, false, VM0_);       // tile nT-2: drain remaining DMA
    TILE_(1, false, VMNOP_);     // tile nT-1

#undef LDA_
#undef LDB_
#undef MFMAQ_
#undef STGA4_
#undef STGB4_
#undef TILE_

    SB_;   // all waves done with LDS buffers (and DMA drained) before alias

    // epilogue: per wave stage 16x64 fp32 in LDS, store coalesced
    float* epw = epi + w * 1088;                    // [16][68]
    const int c8 = (lane & 7) << 3;
    const int r8 = lane >> 3;
    const int colg = col0 + (wn << 6) + c8;
#pragma unroll
    for (int i = 0; i < 8; ++i) {
#pragma unroll
        for (int j = 0; j < 4; ++j)
#pragma unroll
            for (int r = 0; r < 4; ++r) {
                float y = acc[i][j][r];
                if (EPI == 1) y = fmaxf(y, 0.f);
                epw[((q << 2) + r) * 68 + (j << 4) + l15] = y;
            }
        __builtin_amdgcn_wave_barrier();
#pragma unroll
        for (int h = 0; h < 2; ++h) {
            const int rr = r8 + (h << 3);
            F4 f0, f1;
            f0.v = *(const float4*)&epw[rr * 68 + c8];
            f1.v = *(const float4*)&epw[rr * 68 + c8 + 4];
            const int row_out = row0 + (wm << 7) + (i << 4) + rr;
            if (EPI == 0 || EPI == 1) {
                *(uint4*)(Ob + (size_t)row_out * N + colg) = pack8(f0.v, f1.v);
            } else if (EPI == 2) {
                const int bb2 = row_out >> 11;
                const int ls = row_out & 2047;
                const int l = (ls + 8) & 2047;      // reverse shift
                const float mp = maskpad[(bb2 << 11) + l];
                const size_t dst = ((size_t)(bb2 << 11) + l) * (size_t)N + colg;
                F4 x0, x1v;
                x0.v = *(const float4*)(xres + dst);
                x1v.v = *(const float4*)(xres + dst + 4);
                F4 o0, o1;
#pragma unroll
                for (int jj = 0; jj < 4; ++jj) {
                    o0.f[jj] = x0.f[jj]  + f0.f[jj] * mp;
                    o1.f[jj] = x1v.f[jj] + f1.f[jj] * mp;
                }
                *(uint4*)(Ob + dst) = pack8(o0.v, o1.v);
            } else { // EPI 3
                const size_t dst = (size_t)row_out * N + colg;
                U8 pb; pb.v = *(const uint4*)(prevb + dst);
                F4 o0, o1;
#pragma unroll
                for (int jj = 0; jj < 4; ++jj) {
                    o0.f[jj] = bf2f(pb.s[jj])     + f0.f[jj];
                    o1.f[jj] = bf2f(pb.s[4 + jj]) + f1.f[jj];
                }
                *(float4*)(Ofl + dst) = o0.v;
                *(float4*)(Ofl + dst + 4) = o1.v;
            }
        }
        __builtin_amdgcn_wave_barrier();
    }
}

// ---------------- Windowed attention (qkv packed, stride 1536) --------------
// float4-vectorized LDS; row stride 132 floats (528B = 33*16: aligned, and
// 528 % 128 = 16 -> 8 consecutive rows span 8 distinct 16B bank slots).

__global__ __launch_bounds__(256) void attn_kernel(
    const bfu* __restrict__ qkv, const float* __restrict__ mpad,
    bfu* __restrict__ out)
{
    __shared__ float qs[16][132];
    __shared__ float ks[16][132];
    __shared__ float vs[16][132];
    __shared__ float ps[16][17];
    const int t = threadIdx.x;
    const int wg = blockIdx.x;
    const int h = blockIdx.y;
    const int b = wg >> 7;
    const int w = wg & 127;
    const int li = t >> 4;
    const int d0 = (t & 15) << 3;
    const size_t bi = (((size_t)wg << 4) + li) * 1536 + (h << 7) + d0;
    U8 uq, uk, uv;
    uq.v = *(const uint4*)(qkv + bi);
    uk.v = *(const uint4*)(qkv + bi + 512);
    uv.v = *(const uint4*)(qkv + bi + 1024);
    F4 a0, a1;
#pragma unroll
    for (int j = 0; j < 4; ++j) { a0.f[j] = bf2f(uq.s[j]); a1.f[j] = bf2f(uq.s[4 + j]); }
    *(float4*)&qs[li][d0] = a0.v;  *(float4*)&qs[li][d0 + 4] = a1.v;
#pragma unroll
    for (int j = 0; j < 4; ++j) { a0.f[j] = bf2f(uk.s[j]); a1.f[j] = bf2f(uk.s[4 + j]); }
    *(float4*)&ks[li][d0] = a0.v;  *(float4*)&ks[li][d0 + 4] = a1.v;
#pragma unroll
    for (int j = 0; j < 4; ++j) { a0.f[j] = bf2f(uv.s[j]); a1.f[j] = bf2f(uv.s[4 + j]); }
    *(float4*)&vs[li][d0] = a0.v;  *(float4*)&vs[li][d0 + 4] = a1.v;
    __syncthreads();
    const int qi = li, ki = t & 15;
    float s = 0.f;
#pragma unroll
    for (int d = 0; d < 128; d += 4) {
        F4 qv, kv;
        qv.v = *(const float4*)&qs[qi][d];
        kv.v = *(const float4*)&ks[ki][d];
        s += qv.f[0] * kv.f[0] + qv.f[1] * kv.f[1]
           + qv.f[2] * kv.f[2] + qv.f[3] * kv.f[3];
    }
    s *= 0.088388347648318447f;
    const bool lastw = (w == 127);
    if (lastw ? (qi >= 8 && ki >= 8) : (qi < 7 && ki >= 8)) s -= 100.f;
    const int lkey = ((w << 4) + ki + 8) & 2047;
    const bool valid = mpad[(b << 11) + lkey] > 0.f;
    if (!valid) s = -1e30f;
    float mx = s;
#pragma unroll
    for (int o = 8; o > 0; o >>= 1) mx = fmaxf(mx, __shfl_xor(mx, o, 16));
    float e = __expf(s - mx);
    float sum = e;
#pragma unroll
    for (int o = 8; o > 0; o >>= 1) sum += __shfl_xor(sum, o, 16);
    float p = e / sum;
    if (!valid) p = 0.f;
    ps[qi][ki] = p;
    __syncthreads();
    F4 o0, o1;
#pragma unroll
    for (int j = 0; j < 4; ++j) { o0.f[j] = 0.f; o1.f[j] = 0.f; }
#pragma unroll
    for (int kk = 0; kk < 16; ++kk) {
        const float pw = ps[li][kk];
        F4 v0, v1;
        v0.v = *(const float4*)&vs[kk][d0];
        v1.v = *(const float4*)&vs[kk][d0 + 4];
#pragma unroll
        for (int j = 0; j < 4; ++j) {
            o0.f[j] += pw * v0.f[j];
            o1.f[j] += pw * v1.f[j];
        }
    }
    U8 o8;
#pragma unroll
    for (int j = 0; j < 4; ++j) { o8.s[j] = f2bf(o0.f[j]); o8.s[4 + j] = f2bf(o1.f[j]); }
    *(uint4*)(out + (((size_t)wg << 4) + li) * 512 + (h << 7) + d0) = o8.v;
}

// ---------------- Launch ----------------

extern "C" void kernel_launch(void* const* d_in, const int* in_sizes, int n_in,
                              void* d_out, int out_size, void* d_ws, size_t ws_size,
                              hipStream_t stream)
{
    const float* x    = (const float*)d_in[0];
    const float* mpad = (const float*)d_in[3];
    const float* Wq = (const float*)d_in[4];  const float* bq = (const float*)d_in[5];
    const float* Wk = (const float*)d_in[6];  const float* bk = (const float*)d_in[7];
    const float* Wv = (const float*)d_in[8];  const float* bv = (const float*)d_in[9];
    const float* Wo = (const float*)d_in[10]; const float* bo = (const float*)d_in[11];
    const float* g1 = (const float*)d_in[12]; const float* be1 = (const float*)d_in[13];
    const float* g2 = (const float*)d_in[14]; const float* be2 = (const float*)d_in[15];
    const float* W1 = (const float*)d_in[16]; const float* bf1 = (const float*)d_in[17];
    const float* W2 = (const float*)d_in[18]; const float* bf2 = (const float*)d_in[19];
    float* out = (float*)d_out;

    char* p = (char*)d_ws;
    const size_t MB = (size_t)1 << 20;
    bfu* xn_s = (bfu*)p;                     // @0; later att
    bfu* att  = xn_s;
    bfu* qkv  = (bfu*)(p + 32 * MB);         // 96 MiB, stride 1536
    bfu* x1   = qkv;                         // @32M after attn
    bfu* W1t  = (bfu*)(p + 64 * MB);         // 2 MiB
    bfu* W2t  = (bfu*)(p + 66 * MB);         // 2 MiB
    bfu* xn2  = (bfu*)(p + 96 * MB);         // 32 MiB
    bfu* hreg = (bfu*)(p + 128 * MB);        // 128 MiB; head holds Wqkvt/Wot early
    bfu* Wqkvt = hreg;                       // 1.5 MiB
    bfu* Wot   = hreg + 1536 * 512;          // 0.5 MiB
    float* bqkv = (float*)(hreg + 2048 * 512);  // 6 KiB

    const int M = 32768;
    dim3 blk(256);
    dim3 blk5(512);

    // pack weights/bias
    wconv4_kernel<<<dim3(1024), blk, 0, stream>>>(Wq, Wk, Wv, Wo, Wqkvt, Wot);
    bias_concat_kernel<<<dim3(6), blk, 0, stream>>>(bq, bk, bv, bqkv);

    ln1_shift_kernel<<<8192, blk, 0, stream>>>(x, g1, be1, xn_s);

    // fused QKV: [32768 x 1536], K=512
    mgemm<0><<<dim3(6, 128), blk5, 0, stream>>>(xn_s, Wqkvt, bqkv, qkv, nullptr, nullptr, nullptr, nullptr, M, 1536, 512);

    attn_kernel<<<dim3(2048, 4), blk, 0, stream>>>(qkv, mpad, att);

    // FFN weights into dead qkv region
    wconvffn_kernel<<<dim3(2048), blk, 0, stream>>>(W1, W2, W1t, W2t);

    mgemm<2><<<dim3(2, 128), blk5, 0, stream>>>(att, Wot, bo, x1, nullptr, x, nullptr, mpad, M, 512, 512);

    ln2_kernel<<<8192, blk, 0, stream>>>(x1, g2, be2, xn2);

    mgemm<1><<<dim3(8, 128), blk5, 0, stream>>>(xn2, W1t, bf1, hreg, nullptr, nullptr, nullptr, nullptr, M, 2048, 512);
    mgemm<3><<<dim3(2, 128), blk5, 0, stream>>>(hreg, W2t, bf2, nullptr, out, nullptr, x1, nullptr, M, 512, 2048);
}

// Round 13
// 472.969 us; speedup vs baseline: 1.3469x; 1.0135x over previous
//
#include <hip/hip_runtime.h>
#include <stdint.h>

// SChunkTransformerEncoderLayer: B=16, L=2048, C=512, HEADS=4, DK=128,
// CHUNK=16, nW=128, SHIFT=8. fp32 I/O, bf16 internal, fp32 accum.
// R13: R12 (best: 479us) + bf16-LDS attention:
//   qs/ks/vs stored as raw bf16 (ushort8 per 16B chunk, row stride 136
//   ushorts = 272B; 272%128=16 -> 16 rows spread 2-way over bank quads,
//   free). LDS ops/wave: QK 64->32, PV 32->16, staging 6->3 (attn is
//   LDS-instruction-throughput bound: ~112 ops x 128 waves/CU; the LDS
//   pipe is per-CU while VALU has 4x aggregate capacity, so moving the
//   unpack to VALU is net ~2x on the bound). Same math (bf16 bits were
//   exact in f32), same sync structure. GEMM/LN/wconv untouched from R12.
//
// Workspace (256 MiB):
//   @0    : xn_s (32M)  -> att (32M)
//   @32M  : qkv (96M, stride 1536) -> x1@32M / W1t@64M / W2t@66M / xn2@96M
//   @128M : Wqkvt(1.5M)+Wot(0.5M)+bqkv(6K) -> h (128M)

typedef unsigned short bfu;

using bf16x8 = __attribute__((ext_vector_type(8))) __bf16;
using f32x4  = __attribute__((ext_vector_type(4))) float;

union U8 { uint4 v; unsigned short s[8]; };
union F4 { float4 v; float f[4]; };
union ABFrag { uint4 u; bf16x8 f; };

__device__ __forceinline__ float bf2f(unsigned short u) {
    union { uint32_t i; float f; } c; c.i = ((uint32_t)u) << 16; return c.f;
}
__device__ __forceinline__ unsigned short f2bf(float f) {
    union { float f; uint32_t i; } c; c.f = f;
    uint32_t x = c.i;
    return (unsigned short)((x + 0x7FFFu + ((x >> 16) & 1u)) >> 16);
}
__device__ __forceinline__ uint4 pack8(float4 a, float4 b) {
    U8 o;
    o.s[0] = f2bf(a.x); o.s[1] = f2bf(a.y); o.s[2] = f2bf(a.z); o.s[3] = f2bf(a.w);
    o.s[4] = f2bf(b.x); o.s[5] = f2bf(b.y); o.s[6] = f2bf(b.z); o.s[7] = f2bf(b.w);
    return o.v;
}

#define GLDS16(gp, lp)                                                        \
    __builtin_amdgcn_global_load_lds(                                         \
        (__attribute__((address_space(1))) void*)(gp),                        \
        (__attribute__((address_space(3))) void*)(lp), 16, 0, 0)

// ---- weight packing: 4x 512x512 transposes (Wq,Wk,Wv -> Wqkvt; Wo -> Wot)
// flat grid 1024: z = b>>8 selects matrix, r = b&255 -> 16x16 32-tile grid.

__global__ __launch_bounds__(256) void wconv4_kernel(
    const float* __restrict__ Wq, const float* __restrict__ Wk,
    const float* __restrict__ Wv, const float* __restrict__ Wo,
    bfu* __restrict__ Wqkvt, bfu* __restrict__ Wot)
{
    __shared__ float t[32][33];
    const int b = blockIdx.x;
    const int z = b >> 8;
    const int r = b & 255;
    const float* W = (z == 0) ? Wq : (z == 1) ? Wk : (z == 2) ? Wv : Wo;
    bfu* Wt = (z < 3) ? (Wqkvt + (size_t)z * 512 * 512) : Wot;
    const int bn = (r & 15) << 5;
    const int bk = (r >> 4) << 5;
    const int tx = threadIdx.x & 31, ty = threadIdx.x >> 5;
#pragma unroll
    for (int i = 0; i < 32; i += 8)
        t[ty + i][tx] = W[(size_t)(bk + ty + i) * 512 + bn + tx];
    __syncthreads();
#pragma unroll
    for (int i = 0; i < 32; i += 8)
        Wt[(size_t)(bn + ty + i) * 512 + bk + tx] = f2bf(t[tx][ty + i]);
}

// ---- FFN weight packing: W1 (512x2048 -> W1t[2048][512]) and
// W2 (2048x512 -> W2t[512][2048]) in one flat launch (1024 + 1024 blocks).

__global__ __launch_bounds__(256) void wconvffn_kernel(
    const float* __restrict__ W1, const float* __restrict__ W2,
    bfu* __restrict__ W1t, bfu* __restrict__ W2t)
{
    __shared__ float t[32][33];
    const int b = blockIdx.x;
    const int tx = threadIdx.x & 31, ty = threadIdx.x >> 5;
    if (b < 1024) {            // W1: K=512, N=2048 -> 64 x 16 tiles
        const int bn = (b & 63) << 5;
        const int bk = (b >> 6) << 5;
#pragma unroll
        for (int i = 0; i < 32; i += 8)
            t[ty + i][tx] = W1[(size_t)(bk + ty + i) * 2048 + bn + tx];
        __syncthreads();
#pragma unroll
        for (int i = 0; i < 32; i += 8)
            W1t[(size_t)(bn + ty + i) * 512 + bk + tx] = f2bf(t[tx][ty + i]);
    } else {                   // W2: K=2048, N=512 -> 16 x 64 tiles
        const int r = b - 1024;
        const int bn = (r & 15) << 5;
        const int bk = (r >> 4) << 5;
#pragma unroll
        for (int i = 0; i < 32; i += 8)
            t[ty + i][tx] = W2[(size_t)(bk + ty + i) * 512 + bn + tx];
        __syncthreads();
#pragma unroll
        for (int i = 0; i < 32; i += 8)
            W2t[(size_t)(bn + ty + i) * 2048 + bk + tx] = f2bf(t[tx][ty + i]);
    }
}

__global__ __launch_bounds__(256) void bias_concat_kernel(
    const float* __restrict__ a, const float* __restrict__ b,
    const float* __restrict__ c, float* __restrict__ o)
{
    const int t = blockIdx.x * 256 + threadIdx.x;   // grid 6*256 = 1536
    const float* src = (t < 512) ? a : (t < 1024) ? b : c;
    o[t] = src[t & 511];
}

// ---------------- LayerNorm kernels (one wave per row, 4 rows/block) -------

__global__ __launch_bounds__(256) void ln1_shift_kernel(
    const float* __restrict__ x, const float* __restrict__ g,
    const float* __restrict__ be, bfu* __restrict__ out)
{
    const int ms = (blockIdx.x << 2) + (threadIdx.x >> 6);
    const int b = ms >> 11;
    const int ls = ms & 2047;
    const int l = (ls + 8) & 2047;
    const int c0 = (threadIdx.x & 63) << 3;
    const float* xp = x + ((((size_t)(b << 11)) + l) << 9) + c0;
    F4 f0, f1; f0.v = *(const float4*)xp; f1.v = *(const float4*)(xp + 4);
    float vv[8]; float s = 0.f, sq = 0.f;
#pragma unroll
    for (int j = 0; j < 4; ++j) { vv[j] = f0.f[j]; vv[4 + j] = f1.f[j]; }
#pragma unroll
    for (int j = 0; j < 8; ++j) { s += vv[j]; sq += vv[j] * vv[j]; }
#pragma unroll
    for (int o = 32; o > 0; o >>= 1) { s += __shfl_xor(s, o); sq += __shfl_xor(sq, o); }
    const float mean = s * (1.f / 512.f);
    float var = sq * (1.f / 512.f) - mean * mean;
    var = fmaxf(var, 0.f);
    const float rstd = rsqrtf(var + 1e-12f);
    F4 g0, g1v, b0, b1;
    g0.v = *(const float4*)(g + c0);  g1v.v = *(const float4*)(g + c0 + 4);
    b0.v = *(const float4*)(be + c0); b1.v = *(const float4*)(be + c0 + 4);
    U8 o8;
#pragma unroll
    for (int j = 0; j < 4; ++j) {
        o8.s[j]     = f2bf((vv[j]     - mean) * rstd * g0.f[j]  + b0.f[j]);
        o8.s[4 + j] = f2bf((vv[4 + j] - mean) * rstd * g1v.f[j] + b1.f[j]);
    }
    *(uint4*)(out + (((size_t)ms) << 9) + c0) = o8.v;
}

__global__ __launch_bounds__(256) void ln2_kernel(
    const bfu* __restrict__ x1, const float* __restrict__ g,
    const float* __restrict__ be, bfu* __restrict__ out)
{
    const int ms = (blockIdx.x << 2) + (threadIdx.x >> 6);
    const int c0 = (threadIdx.x & 63) << 3;
    U8 u; u.v = *(const uint4*)(x1 + (((size_t)ms) << 9) + c0);
    float vv[8]; float s = 0.f, sq = 0.f;
#pragma unroll
    for (int j = 0; j < 8; ++j) { float f = bf2f(u.s[j]); vv[j] = f; s += f; sq += f * f; }
#pragma unroll
    for (int o = 32; o > 0; o >>= 1) { s += __shfl_xor(s, o); sq += __shfl_xor(sq, o); }
    const float mean = s * (1.f / 512.f);
    float var = sq * (1.f / 512.f) - mean * mean;
    var = fmaxf(var, 0.f);
    const float rstd = rsqrtf(var + 1e-12f);
    F4 g0, g1v, b0, b1;
    g0.v = *(const float4*)(g + c0);  g1v.v = *(const float4*)(g + c0 + 4);
    b0.v = *(const float4*)(be + c0); b1.v = *(const float4*)(be + c0 + 4);
    U8 o8;
#pragma unroll
    for (int j = 0; j < 4; ++j) {
        o8.s[j]     = f2bf((vv[j]     - mean) * rstd * g0.f[j]  + b0.f[j]);
        o8.s[4 + j] = f2bf((vv[4 + j] - mean) * rstd * g1v.f[j] + b1.f[j]);
    }
    *(uint4*)(out + (((size_t)ms) << 9) + c0) = o8.v;
}

// ---------------- MFMA GEMM: 256x256 tile, 4 single-barrier phases --------
// (R7/R9/R12 structure, verified ~99us big-GEMM, no spill.)
// 8 waves (2Mx4N), wave tile 128x64 = acc[8][4] of 16x16x32 frags, BK=64.
// LDS 128 KiB: buf d at d*64KB; A [256][64]bf16 at +0, B at +32KB.
// Swizzle: LDS row r, 16B-slot s holds global k-chunk (s ^ (r&7)); stage
// linear dest + inverse-swizzled global src; ds_read col ^ ((l15&7)<<4).
// Per K-tile t (buf D=t&1; stage targets t+2 -> same buf D):
//  P0: [bar] rd A(MH0)+B(NH0)          ; MFMA Q(0,0)
//  P1: [bar] rd B(NH1)                 ; MFMA Q(0,1)
//  P2: [bar] rd A(MH1); STAGE B4       ; MFMA Q(1,0)
//  P3: [bar] STAGE A4                  ; MFMA Q(1,1); vmcnt(8)
// EPI 0: Ob=bf16(Y)  1: Ob=bf16(relu Y)
// EPI 2: Ob[unshifted] = bf16(xres + Y*mp)   3: Ofl = bf2f(prevb) + Y

template<int EPI>
__global__ __launch_bounds__(512, 2) void mgemm(
    const bfu* __restrict__ X, const bfu* __restrict__ Wt,
    const float* __restrict__ bias,
    bfu* Ob, float* Ofl,
    const float* __restrict__ xres, const bfu* __restrict__ prevb,
    const float* __restrict__ maskpad,
    int M, int N, int K)
{
    __shared__ __align__(16) char smem[131072];
    bfu* smb = (bfu*)smem;
    const char* smc = (const char*)smem;
    float* epi = (float*)smem;

    const int t = threadIdx.x;
    const int lane = t & 63;
    const int w = t >> 6;              // 0..7
    const int wm = w >> 2, wn = w & 3; // 2 x 4 wave grid
    const int q = lane >> 4, l15 = lane & 15;

    // XCD-aware bijective block swizzle (nwg % 8 == 0 for all our grids)
    const int gx = gridDim.x;
    const int nwg = gx * gridDim.y;
    int wid = blockIdx.y * gx + blockIdx.x;
    wid = ((wid & 7) * (nwg >> 3)) + (wid >> 3);
    const int row0 = (wid / gx) << 8;
    const int col0 = (wid % gx) << 8;

    // staging: thread covers row (stmt*64 + w*8 + lane/8),
    // global chunk (lane&7)^((lane>>3)&7); LDS dest linear lane*16B.
    const int srow = (w << 3) + (lane >> 3);
    const int scol = (((lane & 7) ^ ((lane >> 3) & 7)) << 3);
    const bfu* gA = X  + (size_t)(row0 + srow) * K + scol;
    const bfu* gB = Wt + (size_t)(col0 + srow) * K + scol;
    bfu* lsA0 = smb + (w << 9) + (lane << 3);
    bfu* lsB0 = lsA0 + 16384;
    bfu* lsA1 = lsA0 + 32768;
    bfu* lsB1 = lsA0 + 49152;

    // frag read bases (bytes)
    const int arow = ((wm << 7) + l15) << 7;   // (wm*128+l15)*128
    const int brow = ((wn << 6) + l15) << 7;   // (wn*64 +l15)*128
    const int qb   = q << 4;
    const int swz  = (l15 & 7) << 4;

    // bias preloaded into accumulators
    f32x4 acc[8][4];
    float bv[4];
#pragma unroll
    for (int j = 0; j < 4; ++j) bv[j] = bias[col0 + (wn << 6) + (j << 4) + l15];
#pragma unroll
    for (int i = 0; i < 8; ++i)
#pragma unroll
        for (int j = 0; j < 4; ++j) {
            acc[i][j][0] = bv[j]; acc[i][j][1] = bv[j];
            acc[i][j][2] = bv[j]; acc[i][j][3] = bv[j];
        }

    ABFrag a[4][2];        // current A half (single-buffered - fits budget)
    ABFrag bb[2][2][2];    // full B tile: [NH][nf][kk], register-resident

#define SB_   __builtin_amdgcn_s_barrier()
#define VM8_  asm volatile("s_waitcnt vmcnt(8)" ::: "memory")
#define VM0_  asm volatile("s_waitcnt vmcnt(0)" ::: "memory")
#define VMNOP_ do {} while (0)

#define LDA_(D, MH)                                                           \
    _Pragma("unroll") for (int mf = 0; mf < 4; ++mf)                          \
    _Pragma("unroll") for (int kk = 0; kk < 2; ++kk)                          \
        a[mf][kk].u = *(const uint4*)(smc + (D)*65536 + arow + (MH)*8192 +    \
                                      mf*2048 + (((kk << 6) + qb) ^ swz));
#define LDB_(D, NH)                                                           \
    _Pragma("unroll") for (int nf = 0; nf < 2; ++nf)                          \
    _Pragma("unroll") for (int kk = 0; kk < 2; ++kk)                          \
        bb[NH][nf][kk].u = *(const uint4*)(smc + (D)*65536 + 32768 + brow +   \
                                      (NH)*4096 + nf*2048 +                   \
                                      (((kk << 6) + qb) ^ swz));
#define MFMAQ_(MH, NH)                                                        \
    __builtin_amdgcn_s_setprio(1);                                            \
    _Pragma("unroll") for (int mf = 0; mf < 4; ++mf)                          \
    _Pragma("unroll") for (int nf = 0; nf < 2; ++nf) {                        \
        acc[(MH)*4+mf][(NH)*2+nf] = __builtin_amdgcn_mfma_f32_16x16x32_bf16(  \
            a[mf][0].f, bb[NH][nf][0].f, acc[(MH)*4+mf][(NH)*2+nf], 0, 0, 0); \
        acc[(MH)*4+mf][(NH)*2+nf] = __builtin_amdgcn_mfma_f32_16x16x32_bf16(  \
            a[mf][1].f, bb[NH][nf][1].f, acc[(MH)*4+mf][(NH)*2+nf], 0, 0, 0);}\
    __builtin_amdgcn_s_setprio(0);
#define STGA4_(D, GA2) do {                                                   \
    GLDS16((GA2), lsA##D);                                                    \
    GLDS16((GA2) + (size_t)64  * K, lsA##D + 4096);                           \
    GLDS16((GA2) + (size_t)128 * K, lsA##D + 8192);                           \
    GLDS16((GA2) + (size_t)192 * K, lsA##D + 12288); } while (0)
#define STGB4_(D, GB2) do {                                                   \
    GLDS16((GB2), lsB##D);                                                    \
    GLDS16((GB2) + (size_t)64  * K, lsB##D + 4096);                           \
    GLDS16((GB2) + (size_t)128 * K, lsB##D + 8192);                           \
    GLDS16((GB2) + (size_t)192 * K, lsB##D + 12288); } while (0)
// single-barrier phases; tile t in buf D; stages t+2 -> same buf D
#define TILE_(D, DOSTG, VMW) do {                                             \
    SB_;                                                                      \
    LDA_(D, 0); LDB_(D, 0);                                                   \
    MFMAQ_(0, 0);                                                             \
    SB_;                                                                      \
    LDB_(D, 1);                                                               \
    MFMAQ_(0, 1);                                                             \
    SB_;                                                                      \
    LDA_(D, 1);                                                               \
    if (DOSTG) STGB4_(D, gB2);                                                \
    MFMAQ_(1, 0);                                                             \
    SB_;                                                                      \
    if (DOSTG) STGA4_(D, gA2);                                                \
    MFMAQ_(1, 1);                                                             \
    VMW;                                                                      \
} while (0)

    const int nT = K >> 6;   // K in {512, 2048} -> nT in {8, 32}, even

    // prologue: stage tiles 0 (buf0) and 1 (buf1); per-wave wait for tile0
    // (cross-wave visibility comes from the loop's first P0 barrier)
    STGA4_(0, gA); STGB4_(0, gB);
    {
        const bfu* ga1 = gA + 64; const bfu* gb1 = gB + 64;
        STGA4_(1, ga1); STGB4_(1, gb1);
    }
    VM8_;

    const bfu* gA2 = gA + 128;   // tile 2
    const bfu* gB2 = gB + 128;
#pragma unroll 1
    for (int tt = 0; tt < nT - 2; tt += 2) {
        TILE_(0, true, VM8_);
        gA2 += 64; gB2 += 64;
        TILE_(1, true, VM8_);
        gA2 += 64; gB2 += 64;
    }
    TILE_(0, false, VM0_);       // tile nT-2: drain remaining DMA
    TILE_(1, false, VMNOP_);     // tile nT-1

#undef LDA_
#undef LDB_
#undef MFMAQ_
#undef STGA4_
#undef STGB4_
#undef TILE_

    SB_;   // all waves done with LDS buffers (and DMA drained) before alias

    // epilogue: per wave stage 16x64 fp32 in LDS, store coalesced
    float* epw = epi + w * 1088;                    // [16][68]
    const int c8 = (lane & 7) << 3;
    const int r8 = lane >> 3;
    const int colg = col0 + (wn << 6) + c8;
#pragma unroll
    for (int i = 0; i < 8; ++i) {
#pragma unroll
        for (int j = 0; j < 4; ++j)
#pragma unroll
            for (int r = 0; r < 4; ++r) {
                float y = acc[i][j][r];
                if (EPI == 1) y = fmaxf(y, 0.f);
                epw[((q << 2) + r) * 68 + (j << 4) + l15] = y;
            }
        __builtin_amdgcn_wave_barrier();
#pragma unroll
        for (int h = 0; h < 2; ++h) {
            const int rr = r8 + (h << 3);
            F4 f0, f1;
            f0.v = *(const float4*)&epw[rr * 68 + c8];
            f1.v = *(const float4*)&epw[rr * 68 + c8 + 4];
            const int row_out = row0 + (wm << 7) + (i << 4) + rr;
            if (EPI == 0 || EPI == 1) {
                *(uint4*)(Ob + (size_t)row_out * N + colg) = pack8(f0.v, f1.v);
            } else if (EPI == 2) {
                const int bb2 = row_out >> 11;
                const int ls = row_out & 2047;
                const int l = (ls + 8) & 2047;      // reverse shift
                const float mp = maskpad[(bb2 << 11) + l];
                const size_t dst = ((size_t)(bb2 << 11) + l) * (size_t)N + colg;
                F4 x0, x1v;
                x0.v = *(const float4*)(xres + dst);
                x1v.v = *(const float4*)(xres + dst + 4);
                F4 o0, o1;
#pragma unroll
                for (int jj = 0; jj < 4; ++jj) {
                    o0.f[jj] = x0.f[jj]  + f0.f[jj] * mp;
                    o1.f[jj] = x1v.f[jj] + f1.f[jj] * mp;
                }
                *(uint4*)(Ob + dst) = pack8(o0.v, o1.v);
            } else { // EPI 3
                const size_t dst = (size_t)row_out * N + colg;
                U8 pb; pb.v = *(const uint4*)(prevb + dst);
                F4 o0, o1;
#pragma unroll
                for (int jj = 0; jj < 4; ++jj) {
                    o0.f[jj] = bf2f(pb.s[jj])     + f0.f[jj];
                    o1.f[jj] = bf2f(pb.s[4 + jj]) + f1.f[jj];
                }
                *(float4*)(Ofl + dst) = o0.v;
                *(float4*)(Ofl + dst + 4) = o1.v;
            }
        }
        __builtin_amdgcn_wave_barrier();
    }
}

// ---------------- Windowed attention (qkv packed, stride 1536) --------------
// bf16 LDS: qs/ks/vs hold raw bf16 bits (ushort8 = 8 dims per 16B read).
// Row stride 136 ushorts (272B: 16B-aligned; 272%128=16 -> 16 rows spread
// 2-way over the 8 bank-quads, free). LDS ops/wave: QK 32, PV 16+16(ps),
// staging 3 - roughly half of the f32 version; unpack runs on VALU (4x
// aggregate capacity vs the per-CU LDS pipe).

__global__ __launch_bounds__(256) void attn_kernel(
    const bfu* __restrict__ qkv, const float* __restrict__ mpad,
    bfu* __restrict__ out)
{
    __shared__ bfu qs[16][136];
    __shared__ bfu ks[16][136];
    __shared__ bfu vs[16][136];
    __shared__ float ps[16][17];
    const int t = threadIdx.x;
    const int wg = blockIdx.x;
    const int h = blockIdx.y;
    const int b = wg >> 7;
    const int w = wg & 127;
    const int li = t >> 4;
    const int d0 = (t & 15) << 3;
    const size_t bi = (((size_t)wg << 4) + li) * 1536 + (h << 7) + d0;
    uint4 uq = *(const uint4*)(qkv + bi);
    uint4 uk = *(const uint4*)(qkv + bi + 512);
    uint4 uv = *(const uint4*)(qkv + bi + 1024);
    *(uint4*)&qs[li][d0] = uq;
    *(uint4*)&ks[li][d0] = uk;
    *(uint4*)&vs[li][d0] = uv;
    __syncthreads();
    const int qi = li, ki = t & 15;
    float s = 0.f;
#pragma unroll
    for (int d = 0; d < 128; d += 8) {
        U8 qv, kv;
        qv.v = *(const uint4*)&qs[qi][d];
        kv.v = *(const uint4*)&ks[ki][d];
#pragma unroll
        for (int j = 0; j < 8; ++j)
            s += bf2f(qv.s[j]) * bf2f(kv.s[j]);
    }
    s *= 0.088388347648318447f;
    const bool lastw = (w == 127);
    if (lastw ? (qi >= 8 && ki >= 8) : (qi < 7 && ki >= 8)) s -= 100.f;
    const int lkey = ((w << 4) + ki + 8) & 2047;
    const bool valid = mpad[(b << 11) + lkey] > 0.f;
    if (!valid) s = -1e30f;
    float mx = s;
#pragma unroll
    for (int o = 8; o > 0; o >>= 1) mx = fmaxf(mx, __shfl_xor(mx, o, 16));
    float e = __expf(s - mx);
    float sum = e;
#pragma unroll
    for (int o = 8; o > 0; o >>= 1) sum += __shfl_xor(sum, o, 16);
    float p = e / sum;
    if (!valid) p = 0.f;
    ps[qi][ki] = p;
    __syncthreads();
    float o_[8];
#pragma unroll
    for (int j = 0; j < 8; ++j) o_[j] = 0.f;
#pragma unroll
    for (int kk = 0; kk < 16; ++kk) {
        const float pw = ps[li][kk];
        U8 vv8;
        vv8.v = *(const uint4*)&vs[kk][d0];
#pragma unroll
        for (int j = 0; j < 8; ++j)
            o_[j] += pw * bf2f(vv8.s[j]);
    }
    U8 o8;
#pragma unroll
    for (int j = 0; j < 8; ++j) o8.s[j] = f2bf(o_[j]);
    *(uint4*)(out + (((size_t)wg << 4) + li) * 512 + (h << 7) + d0) = o8.v;
}

// ---------------- Launch ----------------

extern "C" void kernel_launch(void* const* d_in, const int* in_sizes, int n_in,
                              void* d_out, int out_size, void* d_ws, size_t ws_size,
                              hipStream_t stream)
{
    const float* x    = (const float*)d_in[0];
    const float* mpad = (const float*)d_in[3];
    const float* Wq = (const float*)d_in[4];  const float* bq = (const float*)d_in[5];
    const float* Wk = (const float*)d_in[6];  const float* bk = (const float*)d_in[7];
    const float* Wv = (const float*)d_in[8];  const float* bv = (const float*)d_in[9];
    const float* Wo = (const float*)d_in[10]; const float* bo = (const float*)d_in[11];
    const float* g1 = (const float*)d_in[12]; const float* be1 = (const float*)d_in[13];
    const float* g2 = (const float*)d_in[14]; const float* be2 = (const float*)d_in[15];
    const float* W1 = (const float*)d_in[16]; const float* bf1 = (const float*)d_in[17];
    const float* W2 = (const float*)d_in[18]; const float* bf2 = (const float*)d_in[19];
    float* out = (float*)d_out;

    char* p = (char*)d_ws;
    const size_t MB = (size_t)1 << 20;
    bfu* xn_s = (bfu*)p;                     // @0; later att
    bfu* att  = xn_s;
    bfu* qkv  = (bfu*)(p + 32 * MB);         // 96 MiB, stride 1536
    bfu* x1   = qkv;                         // @32M after attn
    bfu* W1t  = (bfu*)(p + 64 * MB);         // 2 MiB
    bfu* W2t  = (bfu*)(p + 66 * MB);         // 2 MiB
    bfu* xn2  = (bfu*)(p + 96 * MB);         // 32 MiB
    bfu* hreg = (bfu*)(p + 128 * MB);        // 128 MiB; head holds Wqkvt/Wot early
    bfu* Wqkvt = hreg;                       // 1.5 MiB
    bfu* Wot   = hreg + 1536 * 512;          // 0.5 MiB
    float* bqkv = (float*)(hreg + 2048 * 512);  // 6 KiB

    const int M = 32768;
    dim3 blk(256);
    dim3 blk5(512);

    // pack weights/bias
    wconv4_kernel<<<dim3(1024), blk, 0, stream>>>(Wq, Wk, Wv, Wo, Wqkvt, Wot);
    bias_concat_kernel<<<dim3(6), blk, 0, stream>>>(bq, bk, bv, bqkv);

    ln1_shift_kernel<<<8192, blk, 0, stream>>>(x, g1, be1, xn_s);

    // fused QKV: [32768 x 1536], K=512
    mgemm<0><<<dim3(6, 128), blk5, 0, stream>>>(xn_s, Wqkvt, bqkv, qkv, nullptr, nullptr, nullptr, nullptr, M, 1536, 512);

    attn_kernel<<<dim3(2048, 4), blk, 0, stream>>>(qkv, mpad, att);

    // FFN weights into dead qkv region
    wconvffn_kernel<<<dim3(2048), blk, 0, stream>>>(W1, W2, W1t, W2t);

    mgemm<2><<<dim3(2, 128), blk5, 0, stream>>>(att, Wot, bo, x1, nullptr, x, nullptr, mpad, M, 512, 512);

    ln2_kernel<<<8192, blk, 0, stream>>>(x1, g2, be2, xn2);

    mgemm<1><<<dim3(8, 128), blk5, 0, stream>>>(xn2, W1t, bf1, hreg, nullptr, nullptr, nullptr, nullptr, M, 2048, 512);
    mgemm<3><<<dim3(2, 128), blk5, 0, stream>>>(hreg, W2t, bf2, nullptr, out, nullptr, x1, nullptr, M, 512, 2048);
}